// Round 6
// baseline (69.566 us; speedup 1.0000x reference)
//
#include <hip/hip_runtime.h>
#include <math.h>

#define NSAMP 524288              // 2^19 samples per channel
#define CHUNK 8                   // samples per thread
#define WGT 256                   // threads per workgroup
#define NWGC 256                  // workgroups per channel
#define TOTWG 512                 // total workgroups (regular launch, 2/CU)
#define HIDDEN 16
#define LS 33                     // LDS row stride (conflict-free)
#define NTAB 512                  // p(theta) lookup table size

__device__ __forceinline__ float fast_tanh(float x) {
    float e = __expf(2.0f * x);
    return (e - 1.0f) / (e + 1.0f);
}

// (Mo,do) = (Ma,da) ∘ (Mb,db): apply b first, then a
__device__ __forceinline__ void compose5(const float* Ma, const float* da,
                                         const float* Mb, const float* db,
                                         float* Mo, float* dout) {
#pragma unroll
    for (int r = 0; r < 5; ++r) {
#pragma unroll
        for (int c = 0; c < 5; ++c) {
            float acc = 0.0f;
#pragma unroll
            for (int k = 0; k < 5; ++k) acc = fmaf(Ma[r*5+k], Mb[k*5+c], acc);
            Mo[r*5+c] = acc;
        }
        float acc = da[r];
#pragma unroll
        for (int k = 0; k < 5; ++k) acc = fmaf(Ma[r*5+k], db[k], acc);
        dout[r] = acc;
    }
}

__global__ void __launch_bounds__(WGT, 2) k_fused(
    const float* __restrict__ X,
    const float* __restrict__ rate01,
    const float* __restrict__ phoff01,
    const float* __restrict__ W1,
    const float* __restrict__ b1,
    const float* __restrict__ W2,
    const float* __restrict__ b2,
    const float* __restrict__ amp,
    const float* __restrict__ bias_,
    const float* __restrict__ depth_,
    const float* __restrict__ g1p,
    const float* __restrict__ prevph,
    float* __restrict__ OUT,
    float* __restrict__ REC,
    unsigned int* __restrict__ FLG,
    unsigned int* __restrict__ TICKET)
{
    __shared__ float Tp[NTAB];        // p(theta) table
    __shared__ float sM[WGT * LS];    // scan buffer (reused by phase C)
    __shared__ unsigned int s_vid;

    const int t = threadIdx.x;

    // ticket -> virtual block id (scheduling-ordered: lookback is deadlock-free)
    if (t == 0)
        s_vid = __hip_atomic_fetch_add(TICKET, 1u, __ATOMIC_RELAXED,
                                       __HIP_MEMORY_SCOPE_AGENT);

    const float two_pi = 6.28318530717958647692f;
    const float rate   = fmaf(rate01[0], 4.9f, 0.1f);
    const float w0rev  = rate / 44100.0f;                    // rev per sample
    const float dscale = depth_[0] * 0.5f;
    const float g1     = g1p[0];
    const float b2v    = b2[0];
    const float ampv   = amp[0];
    const float biasv  = bias_[0];

    // ============ Phase 0: build p(theta) table (2 entries/thread) =========
#pragma unroll
    for (int e = 0; e < NTAB / WGT; ++e) {
        int j = t + e * WGT;
        float lfo = ampv * __cosf((float)j * (two_pi / (float)NTAB));
        float m = b2v;
#pragma unroll
        for (int jj = 0; jj < HIDDEN; ++jj) {
            float h = fast_tanh(fmaf(lfo, W1[jj], b1[jj]));
            m = fmaf(h, W2[jj], m);
        }
        float dd = fmaf(dscale, 1.0f + m, biasv);
        float td = __tanf(dd);
        Tp[j] = fast_tanh((1.0f - td) / (1.0f + td));
    }
    __syncthreads();                  // Tp ready, s_vid visible

    const unsigned int vid = s_vid;
    const int c  = (int)(vid >> 8);   // NWGC = 256
    const int wc = (int)(vid & (NWGC - 1));
    const int gblk = wc * WGT + t;    // this thread's block idx within channel
    const long base = (long)c * NSAMP + (long)gblk * CHUNK;
    const float phrev = prevph[0] * (1.0f / two_pi) + (c ? phoff01[0] : 0.0f);

    // ============ Phase A: per-sample coefficient via table lookup =========
    float pv[CHUNK];
#pragma unroll
    for (int k = 0; k < CHUNK; ++k) {
        float ph = fmaf(w0rev, (float)(gblk * CHUNK + k + 1), phrev);
        float u = (ph - floorf(ph)) * (float)NTAB;
        int i0 = ((int)u) & (NTAB - 1);
        float f = u - floorf(u);
        int i1 = (i0 + 1) & (NTAB - 1);
        float t0 = Tp[i0];
        pv[k] = fmaf(f, Tp[i1] - t0, t0);
    }

    // ========== Phase B: block transform + intra-WG inclusive scan =========
    float v[6][5];
#pragma unroll
    for (int j = 0; j < 6; ++j)
#pragma unroll
        for (int r = 0; r < 5; ++r) v[j][r] = (j == r) ? 1.0f : 0.0f;

    {
        const float4* Xv = (const float4*)(X + base);
#pragma unroll
        for (int q = 0; q < CHUNK / 4; ++q) {
            float4 x4 = Xv[q];
            float xa[4] = {x4.x, x4.y, x4.z, x4.w};
#pragma unroll
            for (int ii = 0; ii < 4; ++ii) {
                float pp = pv[q*4 + ii], xx = xa[ii];
#pragma unroll
                for (int j = 0; j < 6; ++j) {
                    float xin = (j == 5) ? xx : 0.0f;
                    float u0 = fmaf(g1, v[j][4], xin);
                    float y0 = fmaf(pp, u0 - v[j][1], v[j][0]);
                    float y1 = fmaf(pp, y0 - v[j][2], v[j][1]);
                    float y2 = fmaf(pp, y1 - v[j][3], v[j][2]);
                    float y3 = fmaf(pp, y2 - v[j][4], v[j][3]);
                    v[j][0] = u0; v[j][1] = y0; v[j][2] = y1; v[j][3] = y2; v[j][4] = y3;
                }
            }
        }
    }

    float M[25], d[5];
#pragma unroll
    for (int j = 0; j < 5; ++j)
#pragma unroll
        for (int r = 0; r < 5; ++r) M[r*5+j] = v[j][r];
#pragma unroll
    for (int r = 0; r < 5; ++r) d[r] = v[5][r];

#pragma unroll
    for (int k = 0; k < 25; ++k) sM[t*LS + k] = M[k];
#pragma unroll
    for (int r = 0; r < 5; ++r) sM[t*LS + 25 + r] = d[r];
    __syncthreads();

    for (int off = 1; off < WGT; off <<= 1) {
        float pM[25], pd[5];
        bool act = (t >= off);
        if (act) {
#pragma unroll
            for (int k = 0; k < 25; ++k) pM[k] = sM[(t-off)*LS + k];
#pragma unroll
            for (int r = 0; r < 5; ++r) pd[r] = sM[(t-off)*LS + 25 + r];
        }
        __syncthreads();
        if (act) {
            float Mn[25], dn[5];
            compose5(M, d, pM, pd, Mn, dn);
#pragma unroll
            for (int k = 0; k < 25; ++k) { M[k] = Mn[k]; sM[t*LS + k] = Mn[k]; }
#pragma unroll
            for (int r = 0; r < 5; ++r) { d[r] = dn[r]; sM[t*LS + 25 + r] = dn[r]; }
        }
        __syncthreads();
    }

    // ===== Publish WG aggregate (row WGT-1) with agent-scope stores ========
    if (t < 30) {
        __hip_atomic_store(&REC[(long)vid * 32 + t], sM[(WGT-1)*LS + t],
                           __ATOMIC_RELAXED, __HIP_MEMORY_SCOPE_AGENT);
    }
    // save neighbor's inclusive record before sM is reused by phase C
    float nbr[30];
    if (t > 0) {
#pragma unroll
        for (int k = 0; k < 30; ++k) nbr[k] = sM[(t-1)*LS + k];
    }
    __syncthreads();                  // vmcnt drained -> REC stores complete
    if (t == 0) {
        __threadfence();
        __hip_atomic_store(&FLG[vid], 1u,
                           __ATOMIC_RELEASE, __HIP_MEMORY_SCOPE_AGENT);
    }

    // ==== Phase C: lookback scan of lower-indexed aggregates (no barrier) ===
    {
        float Ms[25], ds[5];
        if (t < wc) {
            const unsigned int* fp = &FLG[c * NWGC + t];
            while (__hip_atomic_load(fp, __ATOMIC_RELAXED,
                                     __HIP_MEMORY_SCOPE_AGENT) == 0u) {
                __builtin_amdgcn_s_sleep(2);
            }
            (void)__hip_atomic_load(fp, __ATOMIC_ACQUIRE,
                                    __HIP_MEMORY_SCOPE_AGENT);
            const float* rp = REC + (long)(c * NWGC + t) * 32;
            float r[30];
#pragma unroll
            for (int k = 0; k < 30; ++k)
                r[k] = __hip_atomic_load(&rp[k], __ATOMIC_RELAXED,
                                         __HIP_MEMORY_SCOPE_AGENT);
#pragma unroll
            for (int k = 0; k < 25; ++k) Ms[k] = r[k];
#pragma unroll
            for (int k = 0; k < 5; ++k) ds[k] = r[25 + k];
        } else {
            // identity: never read by any position < wc
#pragma unroll
            for (int k = 0; k < 25; ++k) Ms[k] = (k % 6 == 0) ? 1.0f : 0.0f;
#pragma unroll
            for (int k = 0; k < 5; ++k) ds[k] = 0.0f;
        }
#pragma unroll
        for (int k = 0; k < 25; ++k) sM[t*LS + k] = Ms[k];
#pragma unroll
        for (int k = 0; k < 5; ++k) sM[t*LS + 25 + k] = ds[k];
        __syncthreads();

        for (int off = 1; off < NWGC; off <<= 1) {
            float pM[25], pd[5];
            bool act = (t >= off);
            if (act) {
#pragma unroll
                for (int k = 0; k < 25; ++k) pM[k] = sM[(t-off)*LS + k];
#pragma unroll
                for (int k = 0; k < 5; ++k) pd[k] = sM[(t-off)*LS + 25 + k];
            }
            __syncthreads();
            if (act) {
                float Mn[25], dn[5];
                compose5(Ms, ds, pM, pd, Mn, dn);
#pragma unroll
                for (int k = 0; k < 25; ++k) { Ms[k] = Mn[k]; sM[t*LS + k] = Mn[k]; }
#pragma unroll
                for (int k = 0; k < 5; ++k) { ds[k] = dn[k]; sM[t*LS + 25 + k] = dn[k]; }
            }
            __syncthreads();
        }
    }

    // WG entry state: exclusive prefix of aggregates applied to zero state
    float sw[5];
#pragma unroll
    for (int r = 0; r < 5; ++r)
        sw[r] = (wc == 0) ? 0.0f : sM[(wc-1)*LS + 25 + r];

    // ====== Phase D: per-thread entry state, run recursion, emit ===========
    float s0, s1, s2, s3, s4;
    if (t == 0) {
        s0 = sw[0]; s1 = sw[1]; s2 = sw[2]; s3 = sw[3]; s4 = sw[4];
    } else {
        float s[5];
#pragma unroll
        for (int r = 0; r < 5; ++r) {
            float acc = nbr[25 + r];
#pragma unroll
            for (int j = 0; j < 5; ++j) acc = fmaf(nbr[r*5 + j], sw[j], acc);
            s[r] = acc;
        }
        s0 = s[0]; s1 = s[1]; s2 = s[2]; s3 = s[3]; s4 = s[4];
    }

    {
        const float4* Xv = (const float4*)(X + base);
        float4* Ov = (float4*)(OUT + base);
#pragma unroll
        for (int q = 0; q < CHUNK / 4; ++q) {
            float4 x4 = Xv[q];
            float xa[4] = {x4.x, x4.y, x4.z, x4.w};
            float oa[4];
#pragma unroll
            for (int ii = 0; ii < 4; ++ii) {
                float pp = pv[q*4 + ii], xx = xa[ii];
                float u0 = fmaf(g1, s4, xx);
                float y0 = fmaf(pp, u0 - s1, s0);
                float y1 = fmaf(pp, y0 - s2, s1);
                float y2 = fmaf(pp, y1 - s3, s2);
                float y3 = fmaf(pp, y2 - s4, s3);
                s0 = u0; s1 = y0; s2 = y1; s3 = y2; s4 = y3;
                oa[ii] = 0.5f * (xx + y3);
            }
            float4 o; o.x = oa[0]; o.y = oa[1]; o.z = oa[2]; o.w = oa[3];
            Ov[q] = o;
        }
    }
}

extern "C" void kernel_launch(void* const* d_in, const int* in_sizes, int n_in,
                              void* d_out, int out_size, void* d_ws, size_t ws_size,
                              hipStream_t stream) {
    const float* x     = (const float*)d_in[0];
    const float* rate  = (const float*)d_in[1];
    const float* phoff = (const float*)d_in[2];
    const float* W1    = (const float*)d_in[3];
    const float* b1    = (const float*)d_in[4];
    const float* W2    = (const float*)d_in[5];
    const float* b2    = (const float*)d_in[6];
    const float* amp   = (const float*)d_in[7];
    const float* bias_ = (const float*)d_in[8];
    const float* depth = (const float*)d_in[9];
    const float* g1    = (const float*)d_in[10];
    const float* pph   = (const float*)d_in[11];
    float* out = (float*)d_out;

    float* REC = (float*)d_ws;                              // TOTWG*32 f (64 KB)
    unsigned int* FLG = (unsigned int*)(REC + (long)TOTWG * 32);  // TOTWG words
    unsigned int* TICKET = FLG + TOTWG;                     // 1 word

    // zero flags + ticket (contiguous) each call; REC is flag-guarded
    hipMemsetAsync(FLG, 0, (TOTWG + 1) * sizeof(unsigned int), stream);

    k_fused<<<dim3(TOTWG), dim3(WGT), 0, stream>>>(
        x, rate, phoff, W1, b1, W2, b2, amp, bias_, depth, g1, pph,
        out, REC, FLG, TICKET);
}

// Round 7
// 41.533 us; speedup vs baseline: 1.6750x; 1.6750x over previous
//
#include <hip/hip_runtime.h>
#include <math.h>

#define NSAMP 524288              // 2^19 samples per channel
#define CHUNK 8                   // samples per thread
#define WGT 256                   // threads per workgroup
#define NWGC 256                  // workgroups per channel
#define TOTWG 512                 // total workgroups (regular launch, 2/CU)
#define HIDDEN 16
#define LS 33                     // LDS row stride (conflict-free)
#define NTAB 512                  // p(theta) lookup table size

__device__ __forceinline__ float fast_tanh(float x) {
    float e = __expf(2.0f * x);
    return (e - 1.0f) / (e + 1.0f);
}

// (Mo,do) = (Ma,da) ∘ (Mb,db): apply b first, then a
__device__ __forceinline__ void compose5(const float* Ma, const float* da,
                                         const float* Mb, const float* db,
                                         float* Mo, float* dout) {
#pragma unroll
    for (int r = 0; r < 5; ++r) {
#pragma unroll
        for (int c = 0; c < 5; ++c) {
            float acc = 0.0f;
#pragma unroll
            for (int k = 0; k < 5; ++k) acc = fmaf(Ma[r*5+k], Mb[k*5+c], acc);
            Mo[r*5+c] = acc;
        }
        float acc = da[r];
#pragma unroll
        for (int k = 0; k < 5; ++k) acc = fmaf(Ma[r*5+k], db[k], acc);
        dout[r] = acc;
    }
}

// relaxed agent-scope helpers (compile to sc1 load/store; NO cache flush)
__device__ __forceinline__ float ld_agent(const float* p) {
    return __hip_atomic_load(p, __ATOMIC_RELAXED, __HIP_MEMORY_SCOPE_AGENT);
}
__device__ __forceinline__ void st_agent(float* p, float v) {
    __hip_atomic_store(p, v, __ATOMIC_RELAXED, __HIP_MEMORY_SCOPE_AGENT);
}
__device__ __forceinline__ unsigned ldu_agent(const unsigned* p) {
    return __hip_atomic_load(p, __ATOMIC_RELAXED, __HIP_MEMORY_SCOPE_AGENT);
}
__device__ __forceinline__ void stu_agent(unsigned* p, unsigned v) {
    __hip_atomic_store(p, v, __ATOMIC_RELAXED, __HIP_MEMORY_SCOPE_AGENT);
}

__global__ void __launch_bounds__(WGT, 2) k_fused(
    const float* __restrict__ X,
    const float* __restrict__ rate01,
    const float* __restrict__ phoff01,
    const float* __restrict__ W1,
    const float* __restrict__ b1,
    const float* __restrict__ W2,
    const float* __restrict__ b2,
    const float* __restrict__ amp,
    const float* __restrict__ bias_,
    const float* __restrict__ depth_,
    const float* __restrict__ g1p,
    const float* __restrict__ prevph,
    float* __restrict__ OUT,
    float* __restrict__ REC,
    float* __restrict__ ES,
    unsigned int* __restrict__ FLG,
    unsigned int* __restrict__ FLG2,
    unsigned int* __restrict__ TICKET)
{
    __shared__ float Tp[NTAB];        // p(theta) table
    __shared__ float sM[WGT * LS];    // scan buffer (masters reuse in phase C)
    __shared__ float sES[8];
    __shared__ unsigned int s_vid;

    const int t = threadIdx.x;

    // ticket -> virtual block id (vid order == scheduling order)
    if (t == 0)
        s_vid = __hip_atomic_fetch_add(TICKET, 1u, __ATOMIC_RELAXED,
                                       __HIP_MEMORY_SCOPE_AGENT);

    const float two_pi = 6.28318530717958647692f;
    const float rate   = fmaf(rate01[0], 4.9f, 0.1f);
    const float w0rev  = rate / 44100.0f;                    // rev per sample
    const float dscale = depth_[0] * 0.5f;
    const float g1     = g1p[0];
    const float b2v    = b2[0];
    const float ampv   = amp[0];
    const float biasv  = bias_[0];

    // ============ Phase 0: build p(theta) table (2 entries/thread) =========
#pragma unroll
    for (int e = 0; e < NTAB / WGT; ++e) {
        int j = t + e * WGT;
        float lfo = ampv * __cosf((float)j * (two_pi / (float)NTAB));
        float m = b2v;
#pragma unroll
        for (int jj = 0; jj < HIDDEN; ++jj) {
            float h = fast_tanh(fmaf(lfo, W1[jj], b1[jj]));
            m = fmaf(h, W2[jj], m);
        }
        float dd = fmaf(dscale, 1.0f + m, biasv);
        float td = __tanf(dd);
        Tp[j] = fast_tanh((1.0f - td) / (1.0f + td));
    }
    __syncthreads();                  // Tp ready, s_vid visible

    const unsigned int vid = s_vid;
    const int c  = (int)(vid >> 8);   // NWGC = 256
    const int wc = (int)(vid & (NWGC - 1));
    const int gblk = wc * WGT + t;    // this thread's block idx within channel
    const long base = (long)c * NSAMP + (long)gblk * CHUNK;
    const float phrev = prevph[0] * (1.0f / two_pi) + (c ? phoff01[0] : 0.0f);

    // ============ Phase A: per-sample coefficient via table lookup =========
    float pv[CHUNK];
#pragma unroll
    for (int k = 0; k < CHUNK; ++k) {
        float ph = fmaf(w0rev, (float)(gblk * CHUNK + k + 1), phrev);
        float u = (ph - floorf(ph)) * (float)NTAB;
        int i0 = ((int)u) & (NTAB - 1);
        float f = u - floorf(u);
        int i1 = (i0 + 1) & (NTAB - 1);
        float t0 = Tp[i0];
        pv[k] = fmaf(f, Tp[i1] - t0, t0);
    }

    // ========== Phase B: block transform + intra-WG inclusive scan =========
    float v[6][5];
#pragma unroll
    for (int j = 0; j < 6; ++j)
#pragma unroll
        for (int r = 0; r < 5; ++r) v[j][r] = (j == r) ? 1.0f : 0.0f;

    {
        const float4* Xv = (const float4*)(X + base);
#pragma unroll
        for (int q = 0; q < CHUNK / 4; ++q) {
            float4 x4 = Xv[q];
            float xa[4] = {x4.x, x4.y, x4.z, x4.w};
#pragma unroll
            for (int ii = 0; ii < 4; ++ii) {
                float pp = pv[q*4 + ii], xx = xa[ii];
#pragma unroll
                for (int j = 0; j < 6; ++j) {
                    float xin = (j == 5) ? xx : 0.0f;
                    float u0 = fmaf(g1, v[j][4], xin);
                    float y0 = fmaf(pp, u0 - v[j][1], v[j][0]);
                    float y1 = fmaf(pp, y0 - v[j][2], v[j][1]);
                    float y2 = fmaf(pp, y1 - v[j][3], v[j][2]);
                    float y3 = fmaf(pp, y2 - v[j][4], v[j][3]);
                    v[j][0] = u0; v[j][1] = y0; v[j][2] = y1; v[j][3] = y2; v[j][4] = y3;
                }
            }
        }
    }

    float M[25], d[5];
#pragma unroll
    for (int j = 0; j < 5; ++j)
#pragma unroll
        for (int r = 0; r < 5; ++r) M[r*5+j] = v[j][r];
#pragma unroll
    for (int r = 0; r < 5; ++r) d[r] = v[5][r];

#pragma unroll
    for (int k = 0; k < 25; ++k) sM[t*LS + k] = M[k];
#pragma unroll
    for (int r = 0; r < 5; ++r) sM[t*LS + 25 + r] = d[r];
    __syncthreads();

    for (int off = 1; off < WGT; off <<= 1) {
        float pM[25], pd[5];
        bool act = (t >= off);
        if (act) {
#pragma unroll
            for (int k = 0; k < 25; ++k) pM[k] = sM[(t-off)*LS + k];
#pragma unroll
            for (int r = 0; r < 5; ++r) pd[r] = sM[(t-off)*LS + 25 + r];
        }
        __syncthreads();
        if (act) {
            float Mn[25], dn[5];
            compose5(M, d, pM, pd, Mn, dn);
#pragma unroll
            for (int k = 0; k < 25; ++k) { M[k] = Mn[k]; sM[t*LS + k] = Mn[k]; }
#pragma unroll
            for (int r = 0; r < 5; ++r) { d[r] = dn[r]; sM[t*LS + 25 + r] = dn[r]; }
        }
        __syncthreads();
    }

    // ===== Publish WG aggregate (row WGT-1), relaxed agent stores ==========
    if (t < 30)
        st_agent(&REC[(long)vid * 32 + t], sM[(WGT-1)*LS + t]);

    // save neighbor's inclusive record (masters clobber sM in phase C)
    float nbr[30];
    if (t > 0) {
#pragma unroll
        for (int k = 0; k < 30; ++k) nbr[k] = sM[(t-1)*LS + k];
    }
    __syncthreads();                  // drains vmcnt -> REC stores complete
    if (t == 0) {
        asm volatile("" ::: "memory");
        stu_agent(&FLG[vid], 1u);     // flag AFTER records are at coherence pt
    }

    // ===== Phase C (master WGs only): scan channel aggregates once =========
    if (wc == 0) {
        // each thread waits for aggregate t of this channel
        const unsigned int* fp = &FLG[c * NWGC + t];
        while (ldu_agent(fp) == 0u) { __builtin_amdgcn_s_sleep(2); }
        asm volatile("" ::: "memory");
        {
            const float* rp = REC + (long)(c * NWGC + t) * 32;
            float r[30];
#pragma unroll
            for (int k = 0; k < 30; ++k) r[k] = ld_agent(&rp[k]);
#pragma unroll
            for (int k = 0; k < 30; ++k) sM[t*LS + k] = r[k];
        }
        float Ms[25], ds[5];
#pragma unroll
        for (int k = 0; k < 25; ++k) Ms[k] = sM[t*LS + k];
#pragma unroll
        for (int k = 0; k < 5; ++k) ds[k] = sM[t*LS + 25 + k];
        __syncthreads();

        for (int off = 1; off < NWGC; off <<= 1) {
            float pM[25], pd[5];
            bool act = (t >= off);
            if (act) {
#pragma unroll
                for (int k = 0; k < 25; ++k) pM[k] = sM[(t-off)*LS + k];
#pragma unroll
                for (int k = 0; k < 5; ++k) pd[k] = sM[(t-off)*LS + 25 + k];
            }
            __syncthreads();
            if (act) {
                float Mn[25], dn[5];
                compose5(Ms, ds, pM, pd, Mn, dn);
#pragma unroll
                for (int k = 0; k < 25; ++k) { Ms[k] = Mn[k]; sM[t*LS + k] = Mn[k]; }
#pragma unroll
                for (int k = 0; k < 5; ++k) { ds[k] = dn[k]; sM[t*LS + 25 + k] = dn[k]; }
            }
            __syncthreads();
        }

        // entry state for WG t of this channel = exclusive d-part
#pragma unroll
        for (int r = 0; r < 5; ++r) {
            float s = (t == 0) ? 0.0f : sM[(t-1)*LS + 25 + r];
            st_agent(&ES[(long)(c * NWGC + t) * 8 + r], s);
        }
        __syncthreads();              // drain vmcnt -> ES stores complete
        asm volatile("" ::: "memory");
        stu_agent(&FLG2[c * NWGC + t], 1u);
    }

    // ===== All WGs: wait for own entry state (one flag, 5 floats) ==========
    if (t == 0) {
        const unsigned int* fp = &FLG2[c * NWGC + wc];
        while (ldu_agent(fp) == 0u) { __builtin_amdgcn_s_sleep(2); }
        asm volatile("" ::: "memory");
    }
    __syncthreads();
    if (t < 5) sES[t] = ld_agent(&ES[(long)(c * NWGC + wc) * 8 + t]);
    __syncthreads();
    float sw[5];
#pragma unroll
    for (int r = 0; r < 5; ++r) sw[r] = sES[r];

    // ====== Phase D: per-thread entry state, run recursion, emit ===========
    float s0, s1, s2, s3, s4;
    if (t == 0) {
        s0 = sw[0]; s1 = sw[1]; s2 = sw[2]; s3 = sw[3]; s4 = sw[4];
    } else {
        float s[5];
#pragma unroll
        for (int r = 0; r < 5; ++r) {
            float acc = nbr[25 + r];
#pragma unroll
            for (int j = 0; j < 5; ++j) acc = fmaf(nbr[r*5 + j], sw[j], acc);
            s[r] = acc;
        }
        s0 = s[0]; s1 = s[1]; s2 = s[2]; s3 = s[3]; s4 = s[4];
    }

    {
        const float4* Xv = (const float4*)(X + base);
        float4* Ov = (float4*)(OUT + base);
#pragma unroll
        for (int q = 0; q < CHUNK / 4; ++q) {
            float4 x4 = Xv[q];
            float xa[4] = {x4.x, x4.y, x4.z, x4.w};
            float oa[4];
#pragma unroll
            for (int ii = 0; ii < 4; ++ii) {
                float pp = pv[q*4 + ii], xx = xa[ii];
                float u0 = fmaf(g1, s4, xx);
                float y0 = fmaf(pp, u0 - s1, s0);
                float y1 = fmaf(pp, y0 - s2, s1);
                float y2 = fmaf(pp, y1 - s3, s2);
                float y3 = fmaf(pp, y2 - s4, s3);
                s0 = u0; s1 = y0; s2 = y1; s3 = y2; s4 = y3;
                oa[ii] = 0.5f * (xx + y3);
            }
            float4 o; o.x = oa[0]; o.y = oa[1]; o.z = oa[2]; o.w = oa[3];
            Ov[q] = o;
        }
    }
}

extern "C" void kernel_launch(void* const* d_in, const int* in_sizes, int n_in,
                              void* d_out, int out_size, void* d_ws, size_t ws_size,
                              hipStream_t stream) {
    const float* x     = (const float*)d_in[0];
    const float* rate  = (const float*)d_in[1];
    const float* phoff = (const float*)d_in[2];
    const float* W1    = (const float*)d_in[3];
    const float* b1    = (const float*)d_in[4];
    const float* W2    = (const float*)d_in[5];
    const float* b2    = (const float*)d_in[6];
    const float* amp   = (const float*)d_in[7];
    const float* bias_ = (const float*)d_in[8];
    const float* depth = (const float*)d_in[9];
    const float* g1    = (const float*)d_in[10];
    const float* pph   = (const float*)d_in[11];
    float* out = (float*)d_out;

    float* REC = (float*)d_ws;                          // TOTWG*32 f (64 KB)
    float* ES  = REC + (long)TOTWG * 32;                // TOTWG*8 f  (16 KB)
    unsigned int* FLG    = (unsigned int*)(ES + (long)TOTWG * 8);
    unsigned int* FLG2   = FLG + TOTWG;
    unsigned int* TICKET = FLG2 + TOTWG;

    // zero both flag arrays + ticket (contiguous)
    hipMemsetAsync(FLG, 0, (2 * TOTWG + 1) * sizeof(unsigned int), stream);

    k_fused<<<dim3(TOTWG), dim3(WGT), 0, stream>>>(
        x, rate, phoff, W1, b1, W2, b2, amp, bias_, depth, g1, pph,
        out, REC, ES, FLG, FLG2, TICKET);
}